// Round 6
// baseline (359.172 us; speedup 1.0000x reference)
//
#include <hip/hip_runtime.h>
#include <hip/hip_bf16.h>

#define V_ 50000
#define E_ 100
#define H_ 128
#define B_ 16
#define S_ 4096

typedef unsigned short u16;
typedef unsigned int   u32;
typedef short bf16x8 __attribute__((ext_vector_type(8)));  // 8 bf16 = 4 VGPRs
typedef float f32x4  __attribute__((ext_vector_type(4)));

__device__ __forceinline__ float bf2f(u16 x) {
  return __uint_as_float(((u32)x) << 16);
}
__device__ __forceinline__ u16 f2bf(float x) {
  __hip_bfloat16 b = __float2bfloat16(x);
  return *reinterpret_cast<u16*>(&b);
}
__device__ __forceinline__ float sigm(float x) { return 1.0f / (1.0f + __expf(-x)); }
__device__ __forceinline__ float tanh_f(float x) {
  float e = __expf(2.0f * x);
  return 1.0f - 2.0f / (e + 1.0f);
}

// ---------------------------------------------------------------------------
// Prep: emb (f32 [V][100]) -> embB (bf16 [V][128], k-padded with 0)
// ---------------------------------------------------------------------------
__global__ void prep_emb(const float* __restrict__ emb, u16* __restrict__ embB) {
  int i = blockIdx.x * 256 + threadIdx.x;          // over V*128
  if (i < V_ * 128) {
    int k = i & 127, t = i >> 7;
    embB[i] = (k < E_) ? f2bf(emb[t * E_ + k]) : (u16)0;
  }
}

// ---------------------------------------------------------------------------
// Prep: W_x (f32 [512][100], o=g*128+h) -> MFMA B-fragment order, bf16:
// Bx[((t*4+s)*64+lane)*8+j] = B[k=s*32+(lane>>4)*8+j][o=t*16+(lane&15)]
// ---------------------------------------------------------------------------
__global__ void prep_bswx(const float* __restrict__ Wx, u16* __restrict__ Bx) {
  int i = blockIdx.x * 256 + threadIdx.x;          // over 32*4*64*8 = 65536
  if (i < 32 * 4 * 64 * 8) {
    int j = i & 7, l = (i >> 3) & 63, s = (i >> 9) & 3, t = i >> 11;
    int k = s * 32 + (l >> 4) * 8 + j;
    int o = t * 16 + (l & 15);
    Bx[i] = (k < E_) ? f2bf(Wx[o * E_ + k]) : (u16)0;
  }
}

// ---------------------------------------------------------------------------
// Prep: Ucat = [Ul; Ur] (k in [0,256)) -> B-fragment order, bf16:
// Bu[((t*8+s)*64+lane)*8+j] = Ucat[k=s*32+(lane>>4)*8+j][gh=t*16+(lane&15)]
// ---------------------------------------------------------------------------
__global__ void prep_bswu(const float* __restrict__ Ul, const float* __restrict__ Ur,
                          u16* __restrict__ Bu) {
  int i = blockIdx.x * 256 + threadIdx.x;          // over 40*8*64*8 = 163840
  if (i < 40 * 8 * 64 * 8) {
    int j = i & 7, l = (i >> 3) & 63, s = (i >> 9) & 7, t = i >> 12;
    int k = s * 32 + (l >> 4) * 8 + j;
    int gh = t * 16 + (l & 15);
    float v = (k < 128) ? Ul[gh * 128 + k] : Ur[gh * 128 + (k - 128)];
    Bu[i] = f2bf(v);
  }
}

// bsum = b_l + b_r (only the sum is ever used)
__global__ void prep_bsum(const float* __restrict__ bl, const float* __restrict__ br,
                          float* __restrict__ bs) {
  int i = blockIdx.x * 256 + threadIdx.x;
  if (i < 5 * H_) bs[i] = bl[i] + br[i];
}

// ---------------------------------------------------------------------------
// xg GEMM via MFMA + LDS transpose to gate-packed layout + fused level0.
// xg row m (ushort4[128]): xg[m][hh] = {pre_i, pre_f, pre_o, pre_u}(hh) (no bs).
// Also computes level-0 h (bf16) and c (f32) in the same epilogue.
// ---------------------------------------------------------------------------
#define XLDS 516   // 32-row LDS tile, row stride padded (u16 units)
__global__ __launch_bounds__(512) void xg_mfma(
    const u16* __restrict__ embB, const u16* __restrict__ Bx,
    const float* __restrict__ bx, const int* __restrict__ seq,
    const float* __restrict__ bs,
    ushort4* __restrict__ xg, u16* __restrict__ h0, float* __restrict__ c0)
{
  __shared__ u16 lds[32 * XLDS];
  const int w = threadIdx.x >> 6, lane = threadIdx.x & 63;
  const int quad = lane >> 4, l15 = lane & 15;
  const int m0 = blockIdx.x * 32;

  f32x4 acc[2][4];
  #pragma unroll
  for (int r = 0; r < 2; ++r)
    #pragma unroll
    for (int t = 0; t < 4; ++t) acc[r][t] = (f32x4){0.f, 0.f, 0.f, 0.f};

  int tok0 = seq[m0 + l15];
  int tok1 = seq[m0 + 16 + l15];
  const u16* a0p = embB + (size_t)tok0 * 128 + quad * 8;
  const u16* a1p = embB + (size_t)tok1 * 128 + quad * 8;

  #pragma unroll
  for (int s = 0; s < 4; ++s) {
    bf16x8 a0 = *reinterpret_cast<const bf16x8*>(a0p + s * 32);
    bf16x8 a1 = *reinterpret_cast<const bf16x8*>(a1p + s * 32);
    #pragma unroll
    for (int ti = 0; ti < 4; ++ti) {
      int t = w * 4 + ti;
      bf16x8 b = *reinterpret_cast<const bf16x8*>(Bx + ((size_t)(t * 4 + s) * 64 + lane) * 8);
      acc[0][ti] = __builtin_amdgcn_mfma_f32_16x16x32_bf16(a0, b, acc[0][ti], 0, 0, 0);
      acc[1][ti] = __builtin_amdgcn_mfma_f32_16x16x32_bf16(a1, b, acc[1][ti], 0, 0, 0);
    }
  }

  // Scatter C fragments into LDS as [mrow][hh*4 + gate]
  const int g = w >> 1;
  #pragma unroll
  for (int ti = 0; ti < 4; ++ti) {
    int o = (w * 4 + ti) * 16 + l15;
    float bxo = bx[o];
    int hhw = (w & 1) * 64 + ti * 16 + l15;
    #pragma unroll
    for (int r = 0; r < 2; ++r)
      #pragma unroll
      for (int reg = 0; reg < 4; ++reg) {
        int mrow = r * 16 + quad * 4 + reg;
        lds[mrow * XLDS + hhw * 4 + g] = f2bf(acc[r][ti][reg] + bxo);
      }
  }
  __syncthreads();

  // Consume: coalesced ushort4 xg store + fused level-0
  #pragma unroll
  for (int i = 0; i < 8; ++i) {
    int pidx = i * 512 + threadIdx.x;
    int m = pidx >> 7, hh = pidx & 127;
    ushort4 v = *reinterpret_cast<const ushort4*>(&lds[m * XLDS + hh * 4]);
    size_t gm = (size_t)(m0 + m);
    xg[gm * 128 + hh] = v;
    float pi = bf2f(v.x) + bs[hh];
    float po = bf2f(v.z) + bs[384 + hh];
    float pu = bf2f(v.w) + bs[512 + hh];
    float c = sigm(pi) * tanh_f(pu);
    float h = sigm(po) * tanh_f(c);
    h0[gm * 128 + hh] = f2bf(h);
    c0[gm * 128 + hh] = c;
  }
}

// ---------------------------------------------------------------------------
// Gather ALL levels' xg rows into dense per-level slices (pure 16B-chunk copy;
// xg rows are already gate-packed). Level decode via clz.
// ---------------------------------------------------------------------------
#define RTOT 65520
__global__ __launch_bounds__(256) void gather_xg(
    const u16* __restrict__ xg, const int* __restrict__ dep,
    u16* __restrict__ xgath)
{
  int t = blockIdx.x * 256 + threadIdx.x;
  int rid = t >> 6;                          // 64 x 16B chunks per 1KB row
  int ck = t & 63;
  if (rid >= RTOT) return;
  u32 x = 65536u - (u32)rid;                 // (16, 65536]
  int l = __clz((int)(x - 1)) - 15;          // level in [1,12]
  int m = rid - 65536 + (65536 >> (l - 1));  // row within level
  int n = S_ >> l;
  int b = m >> (12 - l);
  int j = m & (n - 1);
  int dj = dep[(l - 1) * (S_ / 2) + j];
  const uint4* src = reinterpret_cast<const uint4*>(xg + ((size_t)b * S_ + dj) * 512);
  reinterpret_cast<uint4*>(xgath + (size_t)rid * 512)[ck] = src[ck];
}

// ---------------------------------------------------------------------------
// Levels 1..3 via MFMA, Mtile=64: wave w owns col-offset q=w of every gate,
// 4 row-tiles -> B:MFMA = 1:4, 2x ILP. Mtot % 64 == 0 guaranteed.
// ---------------------------------------------------------------------------
__global__ __launch_bounds__(512, 4) void level_mfma64(
    const ushort4* __restrict__ xgl, const u16* __restrict__ Bu,
    const float* __restrict__ bs,
    const u16* __restrict__ hPrev, const float* __restrict__ cPrev,
    u16* __restrict__ hOut, float* __restrict__ cOut)
{
  const int w = threadIdx.x >> 6, lane = threadIdx.x & 63;
  const int quad = lane >> 4, l15 = lane & 15;
  const int hh = w * 16 + l15;
  const int m0 = blockIdx.x * 64;

  f32x4 acc[4][5];
  #pragma unroll
  for (int r = 0; r < 4; ++r)
    #pragma unroll
    for (int g = 0; g < 5; ++g) acc[r][g] = (f32x4){0.f, 0.f, 0.f, 0.f};

  const u16* ap = hPrev + (size_t)(m0 + l15) * 256 + quad * 8;

  #pragma unroll
  for (int s = 0; s < 8; ++s) {
    bf16x8 a[4];
    #pragma unroll
    for (int r = 0; r < 4; ++r)
      a[r] = *reinterpret_cast<const bf16x8*>(ap + (size_t)r * 16 * 256 + s * 32);
    #pragma unroll
    for (int g = 0; g < 5; ++g) {
      int t = g * 8 + w;
      bf16x8 b = *reinterpret_cast<const bf16x8*>(Bu + ((size_t)(t * 8 + s) * 64 + lane) * 8);
      #pragma unroll
      for (int r = 0; r < 4; ++r)
        acc[r][g] = __builtin_amdgcn_mfma_f32_16x16x32_bf16(a[r], b, acc[r][g], 0, 0, 0);
    }
  }

  float bsv[5];
  #pragma unroll
  for (int g = 0; g < 5; ++g) bsv[g] = bs[g * 128 + hh];

  #pragma unroll
  for (int r = 0; r < 4; ++r) {
    #pragma unroll
    for (int reg = 0; reg < 4; ++reg) {
      int m = m0 + r * 16 + quad * 4 + reg;
      ushort4 v = xgl[(size_t)m * 128 + hh];
      float x0 = bf2f(v.x), x1 = bf2f(v.y), x2 = bf2f(v.z), x3 = bf2f(v.w);
      float pi  = acc[r][0][reg] + x0 + bsv[0];
      float pfl = acc[r][1][reg] + x1 + bsv[1];
      float pfr = acc[r][2][reg] + x1 + bsv[2];
      float po  = acc[r][3][reg] + x2 + bsv[3];
      float pu  = acc[r][4][reg] + x3 + bsv[4];
      float cl = cPrev[(size_t)m * 256 + hh];
      float cr = cPrev[(size_t)m * 256 + 128 + hh];
      float c = sigm(pi) * tanh_f(pu) + sigm(pfl) * cl + sigm(pfr) * cr;
      float h = sigm(po) * tanh_f(c);
      hOut[(size_t)m * 128 + hh] = f2bf(h);
      cOut[(size_t)m * 128 + hh] = c;
    }
  }
}

// ---------------------------------------------------------------------------
// Levels 4..6 via MFMA, Mtile=32 (as round 5).
// ---------------------------------------------------------------------------
__global__ __launch_bounds__(512) void level_mfma(
    const ushort4* __restrict__ xgl, const u16* __restrict__ Bu,
    const float* __restrict__ bs,
    const u16* __restrict__ hPrev, const float* __restrict__ cPrev,
    u16* __restrict__ hOut, float* __restrict__ cOut, int Mtot)
{
  const int w = threadIdx.x >> 6, lane = threadIdx.x & 63;
  const int quad = lane >> 4, l15 = lane & 15;
  const int hh = w * 16 + l15;
  const int m0 = blockIdx.x * 32;

  f32x4 acc[2][5];
  #pragma unroll
  for (int r = 0; r < 2; ++r)
    #pragma unroll
    for (int g = 0; g < 5; ++g) acc[r][g] = (f32x4){0.f, 0.f, 0.f, 0.f};

  const u16* a0p = hPrev + (size_t)(m0 + l15) * 256 + quad * 8;
  const u16* a1p = a0p + 16 * 256;

  #pragma unroll
  for (int s = 0; s < 8; ++s) {
    bf16x8 a0 = *reinterpret_cast<const bf16x8*>(a0p + s * 32);
    bf16x8 a1 = *reinterpret_cast<const bf16x8*>(a1p + s * 32);
    #pragma unroll
    for (int g = 0; g < 5; ++g) {
      int t = g * 8 + w;
      bf16x8 b = *reinterpret_cast<const bf16x8*>(Bu + ((size_t)(t * 8 + s) * 64 + lane) * 8);
      acc[0][g] = __builtin_amdgcn_mfma_f32_16x16x32_bf16(a0, b, acc[0][g], 0, 0, 0);
      acc[1][g] = __builtin_amdgcn_mfma_f32_16x16x32_bf16(a1, b, acc[1][g], 0, 0, 0);
    }
  }

  float bsv[5];
  #pragma unroll
  for (int g = 0; g < 5; ++g) bsv[g] = bs[g * 128 + hh];

  #pragma unroll
  for (int r = 0; r < 2; ++r) {
    #pragma unroll
    for (int reg = 0; reg < 4; ++reg) {
      int m = m0 + r * 16 + quad * 4 + reg;
      ushort4 v = xgl[(size_t)m * 128 + hh];
      float x0 = bf2f(v.x), x1 = bf2f(v.y), x2 = bf2f(v.z), x3 = bf2f(v.w);
      float pi  = acc[r][0][reg] + x0 + bsv[0];
      float pfl = acc[r][1][reg] + x1 + bsv[1];
      float pfr = acc[r][2][reg] + x1 + bsv[2];
      float po  = acc[r][3][reg] + x2 + bsv[3];
      float pu  = acc[r][4][reg] + x3 + bsv[4];
      float cl = cPrev[(size_t)m * 256 + hh];
      float cr = cPrev[(size_t)m * 256 + 128 + hh];
      float c = sigm(pi) * tanh_f(pu) + sigm(pfl) * cl + sigm(pfr) * cr;
      float h = sigm(po) * tanh_f(c);
      hOut[(size_t)m * 128 + hh] = f2bf(h);
      cOut[(size_t)m * 128 + hh] = c;
    }
  }
}

// ---------------------------------------------------------------------------
// Levels 7..12 fused: one block per batch (whole subtree is block-local).
// h/c ping-pong in LDS; level-7 inputs from global (level-6 output);
// writes d_out directly at level 12.
// ---------------------------------------------------------------------------
__global__ __launch_bounds__(512) void deep_fused(
    const ushort4* __restrict__ xgath, const u16* __restrict__ Bu,
    const float* __restrict__ bs,
    const u16* __restrict__ h6, const float* __restrict__ c6,
    float* __restrict__ out)
{
  __shared__ u16  hls[2][32 * 136];   // bf16, row stride 136
  __shared__ float cls[2][32 * 128];  // f32,  row stride 128
  const int b = blockIdx.x;
  const int w = threadIdx.x >> 6, lane = threadIdx.x & 63;
  const int quad = lane >> 4, l15 = lane & 15;
  const int hh = w * 16 + l15;

  float bsv[5];
  #pragma unroll
  for (int g = 0; g < 5; ++g) bsv[g] = bs[g * 128 + hh];

  const int offs[6] = {64512, 65024, 65280, 65408, 65472, 65504};
  int pb = 0;

  for (int lvl = 7; lvl <= 12; ++lvl) {
    const int nb = 4096 >> lvl;                 // 32,16,8,4,2,1
    const int nr = (lvl == 7) ? 2 : 1;

    f32x4 acc[2][5];
    #pragma unroll
    for (int r = 0; r < 2; ++r)
      #pragma unroll
      for (int g = 0; g < 5; ++g) acc[r][g] = (f32x4){0.f, 0.f, 0.f, 0.f};

    for (int s = 0; s < 8; ++s) {
      bf16x8 a[2];
      if (lvl == 7) {
        const u16* ap = h6 + (size_t)(b * 32 + l15) * 256 + s * 32 + quad * 8;
        a[0] = *reinterpret_cast<const bf16x8*>(ap);
        a[1] = *reinterpret_cast<const bf16x8*>(ap + 16 * 256);
      } else {
        int child = 2 * l15 + (s >= 4 ? 1 : 0);
        int kk = (s & 3) * 32 + quad * 8;
        a[0] = *reinterpret_cast<const bf16x8*>(&hls[pb][child * 136 + kk]);
        a[1] = a[0];
      }
      #pragma unroll
      for (int g = 0; g < 5; ++g) {
        int t = g * 8 + w;
        bf16x8 bb = *reinterpret_cast<const bf16x8*>(Bu + ((size_t)(t * 8 + s) * 64 + lane) * 8);
        acc[0][g] = __builtin_amdgcn_mfma_f32_16x16x32_bf16(a[0], bb, acc[0][g], 0, 0, 0);
        if (lvl == 7)
          acc[1][g] = __builtin_amdgcn_mfma_f32_16x16x32_bf16(a[1], bb, acc[1][g], 0, 0, 0);
      }
    }

    const int xo = offs[lvl - 7];
    for (int r = 0; r < nr; ++r) {
      #pragma unroll
      for (int reg = 0; reg < 4; ++reg) {
        int j = r * 16 + quad * 4 + reg;
        if (j < nb) {
          ushort4 v = xgath[(size_t)(xo + b * nb + j) * 128 + hh];
          float x0 = bf2f(v.x), x1 = bf2f(v.y), x2 = bf2f(v.z), x3 = bf2f(v.w);
          float cl, cr;
          if (lvl == 7) {
            cl = c6[(size_t)(b * 32 + j) * 256 + hh];
            cr = c6[(size_t)(b * 32 + j) * 256 + 128 + hh];
          } else {
            cl = cls[pb][(2 * j) * 128 + hh];
            cr = cls[pb][(2 * j + 1) * 128 + hh];
          }
          float pi  = acc[r][0][reg] + x0 + bsv[0];
          float pfl = acc[r][1][reg] + x1 + bsv[1];
          float pfr = acc[r][2][reg] + x1 + bsv[2];
          float po  = acc[r][3][reg] + x2 + bsv[3];
          float pu  = acc[r][4][reg] + x3 + bsv[4];
          float c = sigm(pi) * tanh_f(pu) + sigm(pfl) * cl + sigm(pfr) * cr;
          float h = sigm(po) * tanh_f(c);
          hls[1 - pb][j * 136 + hh] = f2bf(h);
          cls[1 - pb][j * 128 + hh] = c;
          if (lvl == 12) {
            out[b * 128 + hh] = h;
            out[2048 + b * 128 + hh] = c;
          }
        }
      }
    }
    __syncthreads();
    pb ^= 1;
  }
}

extern "C" void kernel_launch(void* const* d_in, const int* in_sizes, int n_in,
                              void* d_out, int out_size, void* d_ws, size_t ws_size,
                              hipStream_t stream)
{
  const float* emb = (const float*)d_in[0];
  const float* Wx  = (const float*)d_in[1];
  const float* bx  = (const float*)d_in[2];
  const float* Ul  = (const float*)d_in[3];
  const float* bl  = (const float*)d_in[4];
  const float* Ur  = (const float*)d_in[5];
  const float* br  = (const float*)d_in[6];
  const int* seq = (const int*)d_in[7];
  const int* dep = (const int*)d_in[8];

  char* base = (char*)d_ws;
  // Region 0: embB during xg_mfma; reused as xgath afterwards (stream-ordered).
  u16* embB  = (u16*)base;                                        // 12,800,000 B
  u16* xgath = (u16*)base;                                        // 67,092,480 B
  char* p = base + (size_t)RTOT * 1024;
  u16* BswX = (u16*)p;   p += 131072;
  u16* BswU = (u16*)p;   p += 327680;
  float* bs = (float*)p; p += 4096;
  u16* xg = (u16*)p;     p += (size_t)B_ * S_ * 512 * 2;          // 67,108,864
  u16* hA = (u16*)p;     p += (size_t)B_ * S_ * H_ * 2;           // 16,777,216
  float* cA = (float*)p; p += (size_t)B_ * S_ * H_ * 4;           // 33,554,432
  u16* hB = (u16*)p;     p += (size_t)B_ * (S_ / 2) * H_ * 2;     // 8,388,608
  float* cB = (float*)p; p += (size_t)B_ * (S_ / 2) * H_ * 4;     // 16,777,216

  prep_emb<<<dim3((V_ * 128 + 255) / 256), dim3(256), 0, stream>>>(emb, embB);
  prep_bswx<<<dim3(256), dim3(256), 0, stream>>>(Wx, BswX);
  prep_bswu<<<dim3(640), dim3(256), 0, stream>>>(Ul, Ur, BswU);
  prep_bsum<<<dim3(3), dim3(256), 0, stream>>>(bl, br, bs);

  xg_mfma<<<dim3(B_ * S_ / 32), dim3(512), 0, stream>>>(
      embB, BswX, bx, seq, bs, (ushort4*)xg, hA, cA);
  gather_xg<<<dim3(RTOT / 4), dim3(256), 0, stream>>>(xg, dep, xgath);

  const ushort4* xgath4 = (const ushort4*)xgath;
  u16 *hp = hA, *ho = hB;
  float *cp = cA, *co = cB;
  size_t off = 0;
  for (int l = 1; l <= 3; ++l) {
    int Mtot = B_ * (S_ >> l);
    level_mfma64<<<dim3(Mtot / 64), dim3(512), 0, stream>>>(
        xgath4 + off * 128, BswU, bs, hp, cp, ho, co);
    off += Mtot;
    u16* th = hp; hp = ho; ho = th;
    float* tc = cp; cp = co; co = tc;
  }
  for (int l = 4; l <= 6; ++l) {
    int Mtot = B_ * (S_ >> l);
    level_mfma<<<dim3(Mtot / 32), dim3(512), 0, stream>>>(
        xgath4 + off * 128, BswU, bs, hp, cp, ho, co, Mtot);
    off += Mtot;
    u16* th = hp; hp = ho; ho = th;
    float* tc = cp; cp = co; co = tc;
  }

  // hp/cp now hold level-6 output (1024 rows); levels 7..12 fused per batch.
  deep_fused<<<dim3(16), dim3(512), 0, stream>>>(xgath4, BswU, bs, hp, cp, (float*)d_out);
}